// Round 1
// baseline (2076.191 us; speedup 1.0000x reference)
//
#include <hip/hip_runtime.h>
#include <stdint.h>

typedef __bf16 bf16_t;
typedef __bf16 bf16x8 __attribute__((ext_vector_type(8)));
typedef float floatx16 __attribute__((ext_vector_type(16)));
typedef unsigned int u32;
typedef unsigned long long u64;

#define NPROD 64   // Gx producer WGs
#define H1R   16   // h1 ring depth (per half-slab reuse distance; absorbs L0/L1 jitter)
#define SST   592  // L0 stage row stride (592%128=80 -> measured conflict-free b128)
#define ZST   1104 // L1 z-tile row stride (1104%256=80 -> same residue class)
#define FP    32   // flag padding: 32 u32 = 128 B per flag (one LLC line each)

template<int V> struct IC { static constexpr int value = V; };

struct KParams {
  const int* tok;
  const float* emb;
  const float* W1[4]; const float* b1[4];
  const float* W2[4]; const float* b2[4];
  const float* Wd; const float* bd; const float* Wout; const float* bout;
  float* out;
  uint16_t* h1;      // ring: H1R x [64][256] bf16 (rows 0-31 = half A, 32-63 = half B)
  uint16_t* h2;      // ring: 2   x [64][256] bf16
  u32* fl0;          // 32 flags [half*16+sub], 128B-padded
  u32* fl1;          // 64 flags [half*32+wg1], 128B-padded
  u32* fl0g;         // 16 flags, producer-only mirror (set at B-half completion)
  u32* pflags;       // 512 flags (producers -> L0)
  float* dstage;     // [64][128] fp32
  bf16_t* w1bf;      // [20][1024][16] fragment-ordered x-weights (bf16)
  float* gx;         // ring: R slabs of [64][1024] fp32
  int R;
};

__device__ __forceinline__ float sigf(float x) { return 1.f / (1.f + __expf(-x)); }
__device__ __forceinline__ float tanhf_fast(float x) { return 1.f - 2.f / (__expf(2.f * x) + 1.f); }

__device__ __forceinline__ u32 pack2(float a, float b) {
  uint16_t x = __builtin_bit_cast(uint16_t, (bf16_t)a);
  uint16_t y = __builtin_bit_cast(uint16_t, (bf16_t)b);
  return ((u32)y << 16) | (u32)x;
}
__device__ __forceinline__ float2 u2f2(u64 v) { union { u64 u; float2 f; } x; x.u = v; return x.f; }

// relaxed agent-scope ops: bypass L1/L2, coherent at LLC
__device__ __forceinline__ u32  ald32(const u32* p) { return __hip_atomic_load(p, __ATOMIC_RELAXED, __HIP_MEMORY_SCOPE_AGENT); }
__device__ __forceinline__ void ast32(u32* p, u32 v) { __hip_atomic_store(p, v, __ATOMIC_RELAXED, __HIP_MEMORY_SCOPE_AGENT); }
__device__ __forceinline__ u64  ald64(const u64* p) { return __hip_atomic_load(p, __ATOMIC_RELAXED, __HIP_MEMORY_SCOPE_AGENT); }

// Wave-parallel dataflow wait (wave 0 only, then __syncthreads by caller):
template<int NA, int NB>
__device__ __forceinline__ void waitcond(const u32* fa, u32 na, const u32* fb, u32 nb,
                                         const u32* pc, u32 nc) {
  const int lane = threadIdx.x & 63;
  const u32* ap; u32 need;
  if (lane < NA)           { ap = fa + lane * FP;        need = na; }
  else if (lane < NA + NB) { ap = fb + (lane - NA) * FP; need = nb; }
  else                     { ap = pc;                    need = nc; }
  while (!__all(ald32(ap) >= need)) {}
  __atomic_signal_fence(__ATOMIC_ACQUIRE);
}

// producer-side wait on the 16-flag mirror
__device__ __forceinline__ void waitg16(const u32* fa, u32 na) {
  const int lane = threadIdx.x & 63;
  const u32* ap = fa + (lane & 15) * FP;
  while (!__all(ald32(ap) >= na)) {}
  __atomic_signal_fence(__ATOMIC_ACQUIRE);
}

// ---------------- Layer 0: 16 WGs, 16 units (64 gate cols) x BOTH batch halves,
// half-phases interleaved so half-A's LLC exchange hides under half-B's compute.
__device__ void run_l0(const KParams& p, int sub, char* abuf, float* cst, float* biasl)
{
  const int tid = threadIdx.x;
  const int w = tid >> 6, l = tid & 63, q = l >> 5, lr = l & 31;
  const int nh = w & 1, kh = w >> 1;          // waves: N(2) x K(2)
  const int b2 = tid >> 3, u2 = (tid & 7) * 2;

  if (tid < 64) biasl[tid] = p.b1[tid >> 4][sub * 16 + (tid & 15)];

  // W1 h-part: wave's quarter (cols nh*32+lr, K rows kh*128..+128) in registers
  const int c = nh * 32 + lr;
  const float* Wg = p.W1[c >> 4];
  const int un = sub * 16 + (c & 15);
  bf16x8 wf[8];
#pragma unroll
  for (int s2 = 0; s2 < 8; ++s2)
#pragma unroll
    for (int j = 0; j < 8; ++j) {
      int k = kh * 128 + 16 * s2 + 8 * q + j;
      wf[s2][j] = (bf16_t)Wg[(300 + k) * 256 + un];
    }

  float csA[2] = {0.f, 0.f}, csB[2] = {0.f, 0.f};
  u64 rH[8], rG[4], rHn[8], rGn[4];

  // prologue: wait + prefetch for phase (h=0, s=0)
  if (w == 0) waitcond<16, 32>(p.fl0, 0u, p.fl1, 0u, &p.pflags[0], 1u);
  __syncthreads();
  {
    const u64* hp = (const u64*)(p.h1 + (H1R - 1) * 16384);   // h1_A[-1] = zeros
#pragma unroll
    for (int t = 0; t < 8; ++t) rH[t] = ald64(hp + tid + 256 * t);
    const float* gb = p.gx + (size_t)b2 * 1024 + sub * 64 + u2;
    rG[0] = ald64((const u64*)gb);
    rG[1] = ald64((const u64*)(gb + 16));
    rG[2] = ald64((const u64*)(gb + 32));
    rG[3] = ald64((const u64*)(gb + 48));
  }

  auto phase = [&](auto HC, int s) {
    constexpr int h  = decltype(HC)::value;
    constexpr int hn = 1 - h;
    const int sn = h ? (s + 1) : s;            // next phase (hn, sn)
    const bool haveNext = !(h == 1 && s == 511);

    // ---- stage prefetched half (32x256 bf16) into LDS ----
#pragma unroll
    for (int t = 0; t < 8; ++t) {
      int i = tid + 256 * t, r = i >> 6, cc = i & 63;
      *(u64*)(abuf + r * SST + cc * 8) = rH[t];
    }
    __syncthreads();

    // ---- early probe-load for next-phase flags (latency hidden under MFMA) ----
    const u32* pollp = &p.pflags[0]; u32 need = 0u, fpre = 1u;
    if (w == 0 && haveNext) {
      if (l < 16)      { pollp = p.fl0 + (hn * 16 + l) * FP;        need = (u32)sn; }
      else if (l < 48) { pollp = p.fl1 + (hn * 32 + (l - 16)) * FP;
                         need = (sn >= H1R) ? (u32)(sn - (H1R - 1)) : 0u; }  // ring guard
      else             { pollp = &p.pflags[sn * FP];                need = 1u; }
      fpre = ald32(pollp);
    }

    // ---- MFMA: M=32, this wave N=32, K=128 ----
    floatx16 acc;
#pragma unroll
    for (int e = 0; e < 16; ++e) acc[e] = 0.f;
    const char* arow = abuf + lr * SST + kh * 256 + q * 16;
#pragma unroll
    for (int s2 = 0; s2 < 8; ++s2) {
      bf16x8 af = *(const bf16x8*)(arow + 32 * s2);
      acc = __builtin_amdgcn_mfma_f32_32x32x16_bf16(af, wf[s2], acc, 0, 0, 0);
    }
#pragma unroll
    for (int e = 0; e < 16; ++e) {
      int ri = (e & 3) + 8 * (e >> 2) + 4 * q;
      cst[kh * 2176 + ri * 68 + nh * 32 + lr] = acc[e];
    }
    if (w == 0 && haveNext) {
      while (!__all(fpre >= need)) fpre = ald32(pollp);
      __atomic_signal_fence(__ATOMIC_ACQUIRE);
    }
    __syncthreads();

    // ---- prefetch next phase (h1_hn[sn-1] + Gx[sn] half hn) ----
    if (haveNext) {
      const u64* hp = (const u64*)(p.h1 + ((sn + H1R - 1) & (H1R - 1)) * 16384) + hn * 2048;
#pragma unroll
      for (int t = 0; t < 8; ++t) rHn[t] = ald64(hp + tid + 256 * t);
      const float* gb = p.gx + (size_t)(sn % p.R) * 65536u + (hn * 32 + b2) * 1024 + sub * 64 + u2;
      rGn[0] = ald64((const u64*)gb);
      rGn[1] = ald64((const u64*)(gb + 16));
      rGn[2] = ald64((const u64*)(gb + 32));
      rGn[3] = ald64((const u64*)(gb + 48));
    }

    // ---- cell: sum 2 K-planes + Gx + bias ----
    {
      float2 gf = u2f2(rG[0]), gi = u2f2(rG[1]), gg = u2f2(rG[2]), go = u2f2(rG[3]);
      const int base = b2 * 68 + u2;
      float2 af0 = *(float2*)&cst[base],      af1 = *(float2*)&cst[2176 + base];
      float2 ai0 = *(float2*)&cst[base + 16], ai1 = *(float2*)&cst[2176 + base + 16];
      float2 ag0 = *(float2*)&cst[base + 32], ag1 = *(float2*)&cst[2176 + base + 32];
      float2 ao0 = *(float2*)&cst[base + 48], ao1 = *(float2*)&cst[2176 + base + 48];
      float csel[2] = { h ? csB[0] : csA[0], h ? csB[1] : csA[1] };
      float hv[2];
#pragma unroll
      for (int j = 0; j < 2; ++j) {
        float fv = j ? (af0.y + af1.y + gf.y) : (af0.x + af1.x + gf.x);
        float iv = j ? (ai0.y + ai1.y + gi.y) : (ai0.x + ai1.x + gi.x);
        float gv = j ? (ag0.y + ag1.y + gg.y) : (ag0.x + ag1.x + gg.x);
        float ov = j ? (ao0.y + ao1.y + go.y) : (ao0.x + ao1.x + go.x);
        float fj = sigf(fv + biasl[u2 + j]);
        float ij = sigf(iv + biasl[16 + u2 + j]);
        float gj = tanhf_fast(gv + biasl[32 + u2 + j]);
        float oj = sigf(ov + biasl[48 + u2 + j]);
        float cn = fj * csel[j] + ij * gj;
        csel[j] = cn;
        hv[j] = oj * tanhf_fast(cn);
      }
      if (h) { csB[0] = csel[0]; csB[1] = csel[1]; }
      else   { csA[0] = csel[0]; csA[1] = csel[1]; }
      uint16_t* hout = p.h1 + (s & (H1R - 1)) * 16384;
      ast32((u32*)(hout + (h * 32 + b2) * 256 + sub * 16 + u2), pack2(hv[0], hv[1]));
    }
    __syncthreads();                       // drains scoped stores + prefetch loads
    if (tid == 0) {
      ast32(&p.fl0[(h * 16 + sub) * FP], (u32)(s + 1));
      if (h == 1) ast32(&p.fl0g[sub * FP], (u32)(s + 1));   // producer mirror
    }
    if (haveNext) {
#pragma unroll
      for (int t = 0; t < 8; ++t) rH[t] = rHn[t];
#pragma unroll
      for (int t = 0; t < 4; ++t) rG[t] = rGn[t];
    }
  };

  for (int s = 0; s < 512; ++s) { phase(IC<0>{}, s); phase(IC<1>{}, s); }
}

// ---------------- Layer 1: 32 WGs, 8 units (32 gate cols) x BOTH halves, K=512
// split across 4 waves (K=128 each), 4 cst planes summed in the cell.
__device__ void run_l1(const KParams& p, int wg1, char* zbuf, float* cst, float* biasl)
{
  const int tid = threadIdx.x;
  const int w = tid >> 6, l = tid & 63, q = l >> 5, lr = l & 31;
  const int kh = w;
  const int b2 = tid >> 2, u2 = (tid & 3) * 2;   // cell mapping (tid<128)

  if (tid < 32) biasl[tid] = p.b2[tid >> 3][wg1 * 8 + (tid & 7)];

  const float* Wg = p.W2[lr >> 3];
  const int un = wg1 * 8 + (lr & 7);
  bf16x8 wf[8];
#pragma unroll
  for (int s2 = 0; s2 < 8; ++s2)
#pragma unroll
    for (int j = 0; j < 8; ++j) {
      int k = kh * 128 + 16 * s2 + 8 * q + j;
      wf[s2][j] = (bf16_t)Wg[k * 256 + un];
    }

  float csA[2] = {0.f, 0.f}, csB[2] = {0.f, 0.f};
  u64 r1[8], r2[8], r1n[8], r2n[8];

  // prologue: phase (0,0) needs h1_A[0] (fl0_A >= 1); h2_A[-1] = zeros
  if (w == 0) waitcond<32, 16>(p.fl1, 0u, p.fl0, 1u, p.fl1, 0u);
  __syncthreads();
  {
    const u64* hp1 = (const u64*)p.h1;                 // h1_A[0] slab 0
    const u64* hp2 = (const u64*)(p.h2 + 16384);       // h2_A[-1] slab 1 (zeros)
#pragma unroll
    for (int t = 0; t < 8; ++t) r1[t] = ald64(hp1 + tid + 256 * t);
#pragma unroll
    for (int t = 0; t < 8; ++t) r2[t] = ald64(hp2 + tid + 256 * t);
  }

  auto phase = [&](auto HC, int s) {
    constexpr int h  = decltype(HC)::value;
    constexpr int hn = 1 - h;
    const int sn = h ? (s + 1) : s;
    const bool haveNext = !(h == 1 && s == 511);

    // ---- stage z half-tile: rows = [h1_h[s] | h2_h[s-1]] ----
#pragma unroll
    for (int t = 0; t < 8; ++t) {
      int i = tid + 256 * t, r = i >> 6, cc = i & 63;
      *(u64*)(zbuf + r * ZST + cc * 8) = r1[t];
    }
#pragma unroll
    for (int t = 0; t < 8; ++t) {
      int i = tid + 256 * t, r = i >> 6, cc = i & 63;
      *(u64*)(zbuf + r * ZST + 512 + cc * 8) = r2[t];
    }
    __syncthreads();

    const u32* pollp = p.fl1; u32 need = 0u, fpre = 1u;
    if (w == 0 && haveNext) {
      if (l < 32)      { pollp = p.fl1 + (hn * 32 + l) * FP;        need = (u32)sn; }
      else if (l < 48) { pollp = p.fl0 + (hn * 16 + (l - 32)) * FP; need = (u32)(sn + 1); }
      fpre = ald32(pollp);
    }

    floatx16 acc;
#pragma unroll
    for (int e = 0; e < 16; ++e) acc[e] = 0.f;
    const char* arow = zbuf + lr * ZST + kh * 256 + q * 16;
#pragma unroll
    for (int s2 = 0; s2 < 8; ++s2) {
      bf16x8 af = *(const bf16x8*)(arow + 32 * s2);
      acc = __builtin_amdgcn_mfma_f32_32x32x16_bf16(af, wf[s2], acc, 0, 0, 0);
    }
#pragma unroll
    for (int e = 0; e < 16; ++e) {
      int ri = (e & 3) + 8 * (e >> 2) + 4 * q;
      cst[kh * 1152 + ri * 36 + lr] = acc[e];
    }
    if (w == 0 && haveNext) {
      while (!__all(fpre >= need)) fpre = ald32(pollp);
      __atomic_signal_fence(__ATOMIC_ACQUIRE);
    }
    __syncthreads();

    // ---- prefetch next phase ----
    if (haveNext) {
      const u64* hp1 = (const u64*)(p.h1 + (sn & (H1R - 1)) * 16384) + hn * 2048;
      const u64* hp2 = (const u64*)(p.h2 + ((sn + 1) & 1) * 16384) + hn * 2048;
#pragma unroll
      for (int t = 0; t < 8; ++t) r1n[t] = ald64(hp1 + tid + 256 * t);
#pragma unroll
      for (int t = 0; t < 8; ++t) r2n[t] = ald64(hp2 + tid + 256 * t);
    }

    // ---- cell: sum 4 K-planes + bias (threads 0..127) ----
    if (tid < 128) {
      const int base = b2 * 36 + u2;
      float2 vf = {0.f, 0.f}, vi = {0.f, 0.f}, vg = {0.f, 0.f}, vo = {0.f, 0.f};
#pragma unroll
      for (int pl = 0; pl < 4; ++pl) {
        const float* cp = cst + pl * 1152 + base;
        float2 a  = *(const float2*)(cp +  0); vf.x += a.x;  vf.y += a.y;
        float2 b  = *(const float2*)(cp +  8); vi.x += b.x;  vi.y += b.y;
        float2 g2 = *(const float2*)(cp + 16); vg.x += g2.x; vg.y += g2.y;
        float2 o2 = *(const float2*)(cp + 24); vo.x += o2.x; vo.y += o2.y;
      }
      float csel[2] = { h ? csB[0] : csA[0], h ? csB[1] : csA[1] };
      float hv[2];
#pragma unroll
      for (int j = 0; j < 2; ++j) {
        float fj = sigf((j ? vf.y : vf.x) + biasl[u2 + j]);
        float ij = sigf((j ? vi.y : vi.x) + biasl[8 + u2 + j]);
        float gj = tanhf_fast((j ? vg.y : vg.x) + biasl[16 + u2 + j]);
        float oj = sigf((j ? vo.y : vo.x) + biasl[24 + u2 + j]);
        float cn = fj * csel[j] + ij * gj;
        csel[j] = cn;
        hv[j] = oj * tanhf_fast(cn);
      }
      if (h) { csB[0] = csel[0]; csB[1] = csel[1]; }
      else   { csA[0] = csel[0]; csA[1] = csel[1]; }
      uint16_t* hout = p.h2 + (s & 1) * 16384;
      ast32((u32*)(hout + (h * 32 + b2) * 256 + wg1 * 8 + u2), pack2(hv[0], hv[1]));
    }
    __syncthreads();
    if (tid == 0) ast32(&p.fl1[(h * 32 + wg1) * FP], (u32)(s + 1));
    if (haveNext) {
#pragma unroll
      for (int t = 0; t < 8; ++t) { r1[t] = r1n[t]; r2[t] = r2n[t]; }
    }
  };

  for (int s = 0; s < 512; ++s) { phase(IC<0>{}, s); phase(IC<1>{}, s); }

  // ---- dense head part 1: 4 cols of d = relu(h2_last @ Wd + bd) -------------
  if (w == 0) waitcond<64, 0>(p.fl1, 512u, p.fl1, 0u, p.fl1, 0u);
  __syncthreads();
  {
    const u64* hp = (const u64*)(p.h2 + 16384);   // h2[511] slab 1
    u64 tmp[16];
#pragma unroll
    for (int t = 0; t < 16; ++t) tmp[t] = ald64(hp + tid + 256 * t);
#pragma unroll
    for (int t = 0; t < 16; ++t) {
      int i = tid + 256 * t, b = i >> 6, cc = i & 63;
      *(u64*)(zbuf + b * 520 + cc * 8) = tmp[t];
    }
  }
  __syncthreads();
  {
    int b = tid >> 2, cc = wg1 * 4 + (tid & 3);
    const bf16_t* hrow = (const bf16_t*)(zbuf + b * 520);
    float a = p.bd[cc];
#pragma unroll 8
    for (int k = 0; k < 256; ++k) a += (float)hrow[k] * p.Wd[k * 128 + cc];
    ast32((u32*)&p.dstage[b * 128 + cc], __builtin_bit_cast(u32, fmaxf(a, 0.f)));
  }
  __syncthreads();
  if (tid == 0) ast32(&p.fl1[wg1 * FP], 513u);

  // ---- final: out = sigmoid(d @ Wout + bout), by L1 WG 0 --------------------
  if (wg1 == 0) {
    if (w == 0) waitcond<32, 0>(p.fl1, 513u, p.fl1, 0u, p.fl1, 0u);
    __syncthreads();
    if (tid < 64) {
      float a = p.bout[0];
#pragma unroll 8
      for (int cc = 0; cc < 128; ++cc) {
        u32 dv = ald32((u32*)&p.dstage[tid * 128 + cc]);
        a += __builtin_bit_cast(float, dv) * p.Wout[cc];
      }
      p.out[tid] = sigf(a);
    }
  }
}

// ---------------- Gx producers: Gx[s] = x_s @ W1x, K=300 (pad 320) -------------
__device__ void run_prod(const KParams& p, int pw, char* smem)
{
  const int tid = threadIdx.x;
  const int w = tid >> 6, l = tid & 63, q = l >> 5, lr = l & 31;
  const int mh = w & 1, chalf = w >> 1;
  const int R = p.R;

  for (int jj = 0; jj < 512 / NPROD; ++jj) {
    const int s = pw + NPROD * jj;
    if (s >= R) {  // ring throttle via producer-only mirror
      if (w == 0) waitg16(p.fl0g, (u32)(s - R + 1));
    }
    __syncthreads();
    {
      int b = tid >> 2, qq = tid & 3;
      int tokv = p.tok[b * 512 + s];
      const float4* src = (const float4*)(p.emb + (size_t)tokv * 300);
      char* dst = smem + b * 656;
      for (int j2 = qq; j2 < 75; j2 += 4) {
        float4 v = src[j2];
        *(u32*)(dst + 8 * j2)     = pack2(v.x, v.y);
        *(u32*)(dst + 8 * j2 + 4) = pack2(v.z, v.w);
      }
      for (int i = tid; i < 640; i += 256) {
        int bb = i / 10, cc2 = i % 10;
        *(u32*)(smem + bb * 656 + 600 + cc2 * 4) = 0u;
      }
    }
    __syncthreads();

    bf16x8 afr[20];
    const char* arow = smem + (mh * 32 + lr) * 656 + q * 16;
#pragma unroll
    for (int kt = 0; kt < 20; ++kt) afr[kt] = *(const bf16x8*)(arow + 32 * kt);

    float* slab = p.gx + (size_t)(s % R) * 65536u;
    for (int c2 = 0; c2 < 16; ++c2) {
      int n = (chalf * 16 + c2) * 32 + lr;
      floatx16 acc;
#pragma unroll
      for (int e = 0; e < 16; ++e) acc[e] = 0.f;
#pragma unroll
      for (int kt = 0; kt < 20; ++kt) {
        bf16x8 bf = ((const bf16x8*)p.w1bf)[(kt * 1024 + n) * 2 + q];
        acc = __builtin_amdgcn_mfma_f32_32x32x16_bf16(afr[kt], bf, acc, 0, 0, 0);
      }
#pragma unroll
      for (int e = 0; e < 16; ++e) {
        int ri = (e & 3) + 8 * (e >> 2) + 4 * q;
        ast32((u32*)(slab + (mh * 32 + ri) * 1024 + n), __builtin_bit_cast(u32, acc[e]));
      }
    }
    __syncthreads();                    // drains Gx scoped stores
    if (tid == 0) ast32(&p.pflags[s * FP], 1u);
  }
}

__global__ __launch_bounds__(256, 1) void lstm_main(KParams p)
{
  __shared__ __align__(16) char smem[64 * 656];   // L0 stage / L1 z-tile / producer buf / head stage
  __shared__ float cst[4608];                     // L0: 2x[32][68]; L1: 4x[32][36]
  __shared__ float biasl[64];
  const int wg = blockIdx.x;
  if (wg < 16)       run_l0(p, wg, smem, cst, biasl);
  else if (wg < 48)  run_l1(p, wg - 16, smem, cst, biasl);
  else               run_prod(p, wg - 48, smem);
}

// One-time: W1 x-part (rows 0..299, zero-pad to 320) -> bf16 fragment order.
__global__ void prep_w(KParams p) {
  int idx = blockIdx.x * 256 + threadIdx.x;
  if (idx >= 20 * 1024 * 16) return;
  int kk = idx & 15, n = (idx >> 4) & 1023, kt = idx >> 14;
  int k = kt * 16 + kk;
  int g = (n >> 4) & 3, su = n >> 6, u = n & 15;
  float v = (k < 300) ? p.W1[g][k * 256 + su * 16 + u] : 0.f;
  p.w1bf[idx] = (bf16_t)v;
}

// Zero h rings + all flags (ws is re-poisoned before every launch)
__global__ void init_ws(u32* ws32) {
  int i = blockIdx.x * 256 + threadIdx.x;
  if (i < 167424) ws32[i] = 0u;   // [0, 669696): h1, h2, fl0, fl1, fl0g, pflags
}

extern "C" void kernel_launch(void* const* d_in, const int* in_sizes, int n_in,
                              void* d_out, int out_size, void* d_ws, size_t ws_size,
                              hipStream_t stream)
{
  KParams p;
  p.tok = (const int*)d_in[0];
  p.emb = (const float*)d_in[1];
  for (int g = 0; g < 4; ++g) {
    p.W1[g] = (const float*)d_in[2 + 2 * g];
    p.b1[g] = (const float*)d_in[3 + 2 * g];
    p.W2[g] = (const float*)d_in[10 + 2 * g];
    p.b2[g] = (const float*)d_in[11 + 2 * g];
  }
  p.Wd   = (const float*)d_in[18];
  p.bd   = (const float*)d_in[19];
  p.Wout = (const float*)d_in[20];
  p.bout = (const float*)d_in[21];
  p.out  = (float*)d_out;

  char* ws = (char*)d_ws;
  p.h1     = (uint16_t*)ws;               // 16 x 32768 B  -> 524288
  p.h2     = (uint16_t*)(ws + 524288);    // 2 x 32768 B   -> 589824
  p.fl0    = (u32*)(ws + 589824);         // 32 x 128 B    -> 593920
  p.fl1    = (u32*)(ws + 593920);         // 64 x 128 B    -> 602112
  p.fl0g   = (u32*)(ws + 602112);         // 16 x 128 B    -> 604160
  p.pflags = (u32*)(ws + 604160);         // 512 x 128 B   -> 669696
  p.dstage = (float*)(ws + 669696);       // 32768 B       -> 702464
  p.w1bf   = (bf16_t*)(ws + 702464);      // 655360 B      -> 1357824
  p.gx     = (float*)(ws + 1357824);      // ring: R slabs of [64][1024] fp32

  long avail = (long)ws_size - 1357824L;
  int R = (int)(avail / 262144L);
  if (R > 64) R = 64;
  if (R < 1)  R = 1;
  p.R = R;

  hipLaunchKernelGGL(init_ws, dim3(654), dim3(256), 0, stream, (u32*)d_ws);
  hipLaunchKernelGGL(prep_w, dim3(1280), dim3(256), 0, stream, p);
  hipLaunchKernelGGL(lstm_main, dim3(16 + 32 + NPROD), dim3(256), 0, stream, p);
}